// Round 1
// baseline (514.928 us; speedup 1.0000x reference)
//
#include <hip/hip_runtime.h>
#include <hip/hip_cooperative_groups.h>

namespace cg = cooperative_groups;

// CTC batch cost (keras ctc_batch_cost), forward alpha recursion.
// B=128, T=512, C=1024, L=64, S=2L+1=129, blank = C-1.
//
// R7: cooperative full-chip gather. R6 used 128 blocks x 1024 threads ->
// only 128 of 256 CUs active during the HBM-bound scattered gather
// (~185 MB effective fetch; random labels touch ~90% of y_pred's lines).
// Now 256 blocks x 512 threads (1 per CU):
//   blocks 0..127  (owners, batch b): wave 0 runs the R6 recursion
//     (verified exact, absmax=0); waves 1..7 gather chunks 0..3 into LDS.
//   blocks 128..255 (helpers, batch b): gather chunks 4..7, convert to
//     log2, write dense E rows to a static __device__ buffer (8.7 MB,
//     L3-resident; NOT in d_ws, so harness re-poison can't corrupt it).
// One grid.sync() rendezvous (helper: threadfence+sync after writes;
// owner: sync at iteration c==3 before the first E->LDS copy). Owners
// pipeline chunks 4..7 by flat coalesced E->LDS copies (L3 hits) under
// the recursion, reusing R6's per-chunk double-buffer + __syncthreads.
//
// Recursion: lane i owns extended states {2i, 2i+1}; lane 63 also owns
// state 128. Cross-lane dep via DPP wave_shr:1. Log2 domain throughout;
// ln alpha = log2 alpha * ln2 restored at the final loss.
//
// Inputs: d_in[0] y_true i32[B,L]; d_in[1] y_pred f32[B,T,C];
//         d_in[2] input_length i32[B,1]; d_in[3] label_length i32[B,1].
// Output: float [B,1].

constexpr int Tmax   = 512;
constexpr int Cch    = 1024;
constexpr int Lm     = 64;
constexpr int BLANKC = Cch - 1;
constexpr int CH     = 64;            // timesteps per chunk
constexpr int NCH    = Tmax / CH;     // 8
constexpr int SPLIT  = 4;             // chunks [0,SPLIT) owner LDS-gather; rest helper
constexpr int ROW    = 66;            // row stride: 64 labels + blank + pad
constexpr int NB     = 128;           // batch
constexpr int EROWS  = Tmax - SPLIT * CH;   // 256 rows per batch in gE

#define NEGF (-1e9f)
#define EPSF (1e-7f)
#define LN2F (0.69314718055994530942f)

// helper->owner staging for chunks [SPLIT, NCH): log2 emissions, stride ROW.
__device__ float gE[(size_t)NB * EROWS * ROW];   // 8.65 MB, L3-resident

__device__ __forceinline__ float wave_shr1(float src, float fill) {
    int r = __builtin_amdgcn_update_dpp(__float_as_int(fill), __float_as_int(src),
                                        0x138, 0xf, 0xf, false);
    return __int_as_float(r);
}
__device__ __forceinline__ float lae2(float a, float b) {
    float m = fmaxf(a, b);
    return m + __builtin_log2f(__builtin_exp2f(a - m) + __builtin_exp2f(b - m));
}
__device__ __forceinline__ float lse3_2(float a, float b, float c) {
    float m = fmaxf(fmaxf(a, b), c);
    return m + __builtin_log2f(__builtin_exp2f(a - m) +
                               __builtin_exp2f(b - m) +
                               __builtin_exp2f(c - m));
}
__device__ __forceinline__ int clampi(int v, int lo, int hi) {
    return v < lo ? lo : (v > hi ? hi : v);
}

__global__ __launch_bounds__(512, 1) void ctc_coop(
    const int*   __restrict__ y_true,
    const float* __restrict__ y_pred,
    const int*   __restrict__ in_len,
    const int*   __restrict__ lab_len,
    float*       __restrict__ out)
{
    const int  bid   = blockIdx.x;
    const bool owner = bid < NB;
    const int  b     = owner ? bid : bid - NB;
    const int  tid   = threadIdx.x;
    const int  wave  = tid >> 6;
    const int  lane  = tid & 63;

    __shared__ float Ebuf[2][CH * ROW];     // 33.8 KB (owners only use it)

    const int cls = y_true[b * Lm + lane];  // label of odd state 2*lane+1
    const int Tb  = clampi(in_len[b], 0, Tmax);
    const float* __restrict__ base = y_pred + (size_t)b * Tmax * Cch;

    cg::grid_group grid = cg::this_grid();

    if (!owner) {
        // ---- helper: gather chunks [SPLIT, NCH) of batch b into gE ----
        // 8 waves; wave w handles rows tt = w + 8k, k=0..7.
        for (int c = SPLIT; c < NCH; ++c) {
            const int tbase = c * CH;
            if (tbase >= Tb) break;
            float pc[8], pb[8];
#pragma unroll
            for (int k = 0; k < 8; ++k) {
                const int tt = wave + 8 * k;
                if (tbase + tt < Tb) {
                    const float* row = base + (size_t)(tbase + tt) * Cch;
                    pc[k] = row[cls];
                    pb[k] = row[BLANKC];    // uniform address -> broadcast
                }
            }
            float* dstc = gE + ((size_t)b * EROWS + (size_t)(c - SPLIT) * CH) * ROW;
#pragma unroll
            for (int k = 0; k < 8; ++k) {
                const int tt = wave + 8 * k;
                if (tbase + tt < Tb) {
                    float* dst = dstc + tt * ROW;
                    dst[lane] = __builtin_log2f(pc[k] + EPSF);
                    if (lane == 0) dst[64] = __builtin_log2f(pb[k] + EPSF);
                }
            }
        }
        __threadfence();                    // make gE visible across XCDs
        grid.sync();                        // single rendezvous, then exit
        return;
    }

    // ---- owner: R6 structure with 7 gather waves + E->LDS copies ----
    const int lb = clampi(lab_len[b], 0, Lm);

    // gather chunk c (< SPLIT) from y_pred into Ebuf[c&1]; waves 1..7.
    auto gather_hbm = [&](int c) {
        const int tbase = c * CH;
        const int tt0   = wave - 1;         // 0..6
        float pc[10], pb[10];
#pragma unroll
        for (int k = 0; k < 10; ++k) {
            const int tt = tt0 + 7 * k;
            if (tt < CH) {
                const float* row = base + (size_t)(tbase + tt) * Cch;
                pc[k] = row[cls];
                pb[k] = row[BLANKC];
            }
        }
        float* dst0 = Ebuf[c & 1];
#pragma unroll
        for (int k = 0; k < 10; ++k) {
            const int tt = tt0 + 7 * k;
            if (tt < CH) {
                float* dst = dst0 + tt * ROW;
                dst[lane] = __builtin_log2f(pc[k] + EPSF);
                if (lane == 0) dst[64] = __builtin_log2f(pb[k] + EPSF);
            }
        }
    };

    // copy chunk c (>= SPLIT) from gE into Ebuf[c&1]; threads 64..511,
    // flat coalesced copy (gE row stride == LDS row stride == ROW).
    auto copy_E = [&](int c) {
        const float* src = gE + ((size_t)b * EROWS + (size_t)(c - SPLIT) * CH) * ROW;
        float* dst = Ebuf[c & 1];
        for (int i = tid - 64; i < CH * ROW; i += 448)
            dst[i] = src[i];
    };

    // recursion state (wave 0; harmless elsewhere)
    const int  cls_prev = __shfl_up(cls, 1, 64);
    const bool skip     = (lane >= 1) && (cls != cls_prev);
    const bool val_lo   = (lane <= lb);     // state 2*lane
    const bool val_hi   = (lane <  lb);     // state 2*lane+1
    const bool val_ex   = (lb == Lm);       // state 128 (lane 63)

    float a_lo = (lane == 0) ? 0.f : NEGF;  // virtual alpha_{-1}
    float a_hi = NEGF;
    float a_ex = NEGF;

    if (wave != 0) gather_hbm(0);
    __syncthreads();

    for (int c = 0; c < NCH; ++c) {
        if (c == SPLIT - 1) grid.sync();    // helper's gE chunks now visible
        if (wave == 0) {
            const int tbase = c * CH;
            if (tbase < Tb) {
                const int steps = (Tb - tbase) < CH ? (Tb - tbase) : CH;
                const float* eb = Ebuf[c & 1];
                // depth-4 register ring over LDS rows (chunk fully staged,
                // so rows [0,CH) are always valid to prefetch)
                float rc[4], rb[4];
#pragma unroll
                for (int i = 0; i < 4; ++i) {
                    rc[i] = eb[i * ROW + lane];
                    rb[i] = eb[i * ROW + 64];
                }
                for (int i0 = 0; i0 < CH; i0 += 4) {
#pragma unroll
                    for (int j = 0; j < 4; ++j) {
                        const int i = i0 + j;
                        if (i >= steps) break;
                        const float e_c = rc[j];
                        const float e_b = rb[j];
                        const int tn = i + 4;
                        if (tn < CH) {
                            rc[j] = eb[tn * ROW + lane];
                            rb[j] = eb[tn * ROW + 64];
                        }
                        const float p_hi = wave_shr1(a_hi, NEGF); // state 2i-1
                        float n_lo = e_b + lae2(a_lo, p_hi);
                        float n_hi = e_c + lse3_2(a_hi, a_lo, skip ? p_hi : NEGF);
                        float n_ex = e_b + lae2(a_ex, a_hi);
                        a_lo = val_lo ? n_lo : NEGF;
                        a_hi = val_hi ? n_hi : NEGF;
                        a_ex = val_ex ? n_ex : NEGF;
                    }
                    if (i0 + 4 >= steps) break;
                }
            }
        } else {
            // stage chunk c+1 iff the recursion will consume it
            const int n = c + 1;
            if (n < NCH && n * CH < Tb) {
                if (n < SPLIT) gather_hbm(n);
                else           copy_E(n);
            }
        }
        __syncthreads();   // uniform: all 8 waves, every iteration
    }

    if (wave == 0) {
        const float a_end_blank = (lb == Lm) ? __shfl(a_ex, 63, 64)
                                             : __shfl(a_lo, lb, 64);
        const int   el_lane     = (lb >= 1) ? (lb - 1) : 0;
        const float a_end_label = (lb >= 1) ? __shfl(a_hi, el_lane, 64)
                                            : __shfl(a_lo, 0, 64);
        if (lane == 0) {
            out[b] = -LN2F * lae2(a_end_blank, a_end_label);
        }
    }
}

extern "C" void kernel_launch(void* const* d_in, const int* in_sizes, int n_in,
                              void* d_out, int out_size, void* d_ws, size_t ws_size,
                              hipStream_t stream) {
    const int*   y_true  = (const int*)  d_in[0];
    const float* y_pred  = (const float*)d_in[1];
    const int*   in_len  = (const int*)  d_in[2];
    const int*   lab_len = (const int*)  d_in[3];
    float*       out     = (float*)      d_out;

    void* args[] = {(void*)&y_true, (void*)&y_pred, (void*)&in_len,
                    (void*)&lab_len, (void*)&out};
    hipLaunchCooperativeKernel((void*)ctc_coop, dim3(2 * NB), dim3(512),
                               args, 0, stream);
}

// Round 2
// 483.227 us; speedup vs baseline: 1.0656x; 1.0656x over previous
//
#include <hip/hip_runtime.h>

// CTC batch cost (keras ctc_batch_cost), forward alpha recursion.
// B=128, T=512, C=1024, L=64, S=2L+1=129, blank = C-1.
//
// R8: coalesced gather. R7's rocprof showed the scattered per-lane gather
// (lane reads row[cls[lane]], 64 distinct 64B lines per wave-load) runs at
// 427 GB/s (5% HBM peak) -- TA line-serialization / miss-queue bound, not
// bandwidth bound. Fix: read ENTIRE y_pred rows coalesced (float4/lane,
// ~6 TB/s), stage 4KB row in LDS, gather the 65 needed classes from LDS
// (random-bank read, ~6-way conflict, negligible), write dense log2-domain
// E rows to a static __device__ buffer (17 MB, L2/L3 resident).
//   kernel 1 (ctc_gather): 2048 blocks x 256 thr, one wave per (b,t) row,
//     rows t >= input_length skipped. ~192 MB coalesced read -> ~32 us.
//   kernel 2 (ctc_rec): 128 blocks x 512 thr; wave 0 runs the R6 recursion
//     (verified exact, absmax=0); waves 1..7 float4-copy the next chunk's
//     contiguous E slab (16.9 KB, L3-hit) into the LDS double buffer.
// Sequential launches on one stream (implicit release/acquire between
// dispatches -> cross-XCD coherence of gE). No coop launch, no grid.sync.
//
// Recursion: lane i owns extended states {2i, 2i+1}; lane 63 also owns
// state 128. Cross-lane dep via DPP wave_shr:1. Log2 domain throughout;
// ln alpha = log2 alpha * ln2 restored at the final loss.
//
// Inputs: d_in[0] y_true i32[B,L]; d_in[1] y_pred f32[B,T,C];
//         d_in[2] input_length i32[B,1]; d_in[3] label_length i32[B,1].
// Output: float [B,1].

constexpr int Tmax   = 512;
constexpr int Cch    = 1024;
constexpr int Lm     = 64;
constexpr int BLANKC = Cch - 1;
constexpr int CH     = 64;            // timesteps per chunk (recursion)
constexpr int NCH    = Tmax / CH;     // 8
constexpr int ROW    = 66;            // E row stride: 64 labels + blank + pad
constexpr int NB     = 128;           // batch
constexpr int RPB    = 32;            // rows per gather block

#define NEGF (-1e9f)
#define EPSF (1e-7f)
#define LN2F (0.69314718055994530942f)

// log2-domain emissions E[b][t][0..64]; stride ROW. 17.3 MB, L2/L3 resident.
__device__ __align__(16) float gE[(size_t)NB * Tmax * ROW];

__device__ __forceinline__ float wave_shr1(float src, float fill) {
    int r = __builtin_amdgcn_update_dpp(__float_as_int(fill), __float_as_int(src),
                                        0x138, 0xf, 0xf, false);
    return __int_as_float(r);
}
__device__ __forceinline__ float lae2(float a, float b) {
    float m = fmaxf(a, b);
    return m + __builtin_log2f(__builtin_exp2f(a - m) + __builtin_exp2f(b - m));
}
__device__ __forceinline__ float lse3_2(float a, float b, float c) {
    float m = fmaxf(fmaxf(a, b), c);
    return m + __builtin_log2f(__builtin_exp2f(a - m) +
                               __builtin_exp2f(b - m) +
                               __builtin_exp2f(c - m));
}
__device__ __forceinline__ int clampi(int v, int lo, int hi) {
    return v < lo ? lo : (v > hi ? hi : v);
}

// ---------------- kernel 1: coalesced row gather ----------------
// grid = NB * (Tmax/RPB) blocks, 256 threads (4 waves). Wave w of block
// handles rows t = t0 + 4k + w, k = 0..RPB/4-1. Each row: 4x float4/lane
// coalesced load (4 KB), stage in per-wave LDS buffer, LDS-gather the 64
// labels + blank, write log2 E row. Next row's loads issued before the
// current row's LDS gather (software prefetch).
__global__ __launch_bounds__(256, 8) void ctc_gather(
    const int*   __restrict__ y_true,
    const float* __restrict__ y_pred,
    const int*   __restrict__ in_len)
{
    const int blk  = blockIdx.x;
    const int b    = blk / (Tmax / RPB);
    const int t0   = (blk % (Tmax / RPB)) * RPB;
    const int tid  = threadIdx.x;
    const int wave = tid >> 6;
    const int lane = tid & 63;

    const int Tb = clampi(in_len[b], 0, Tmax);
    if (t0 >= Tb) return;                       // whole block unneeded

    __shared__ float rowbuf[4][Cch];            // 16 KB, one 4KB row per wave

    const int cls = y_true[b * Lm + lane];
    const float* __restrict__ base = y_pred + (size_t)b * Tmax * Cch;

    constexpr int NK = RPB / 4;                 // 8 rows per wave
    float4 v0, v1, v2, v3;

    auto issue = [&](int k) {
        const int t = t0 + 4 * k + wave;
        if (t < Tb) {
            const float4* src = (const float4*)(base + (size_t)t * Cch);
            v0 = src[lane];
            v1 = src[64  + lane];
            v2 = src[128 + lane];
            v3 = src[192 + lane];
        }
    };

    issue(0);
    for (int k = 0; k < NK; ++k) {
        const int t = t0 + 4 * k + wave;
        const bool act = (t < Tb);
        if (act) {
            float4* lbuf = (float4*)rowbuf[wave];
            lbuf[lane]        = v0;
            lbuf[64  + lane]  = v1;
            lbuf[128 + lane]  = v2;
            lbuf[192 + lane]  = v3;
        }
        if (k + 1 < NK) issue(k + 1);           // prefetch next row
        if (act) {
            // wave-synchronous: compiler inserts lgkmcnt wait before reads
            const float pc = rowbuf[wave][cls];
            const float pb = rowbuf[wave][BLANKC];   // uniform -> broadcast
            float* dst = gE + ((size_t)b * Tmax + t) * ROW;
            dst[lane] = __builtin_log2f(pc + EPSF);
            if (lane == 0) dst[64] = __builtin_log2f(pb + EPSF);
        }
    }
}

// ---------------- kernel 2: alpha recursion ----------------
__global__ __launch_bounds__(512, 1) void ctc_rec(
    const int* __restrict__ y_true,
    const int* __restrict__ in_len,
    const int* __restrict__ lab_len,
    float*     __restrict__ out)
{
    const int b    = blockIdx.x;
    const int tid  = threadIdx.x;
    const int wave = tid >> 6;
    const int lane = tid & 63;

    __shared__ float Ebuf[2][CH * ROW];         // 33.8 KB double buffer

    const int cls = y_true[b * Lm + lane];      // label of odd state 2*lane+1
    const int Tb  = clampi(in_len[b], 0, Tmax);
    const int lb  = clampi(lab_len[b], 0, Lm);

    // copy chunk c's E slab (contiguous 64*66 floats, float4-aligned) into
    // Ebuf[c&1]; threads 64..511.
    auto copy_E = [&](int c) {
        const float4* src = (const float4*)(gE + ((size_t)b * Tmax + c * CH) * ROW);
        float4* dst = (float4*)Ebuf[c & 1];
        for (int i = tid - 64; i < CH * ROW / 4; i += 448)
            dst[i] = src[i];
    };

    // recursion state (wave 0; harmless elsewhere)
    const int  cls_prev = __shfl_up(cls, 1, 64);
    const bool skip     = (lane >= 1) && (cls != cls_prev);
    const bool val_lo   = (lane <= lb);         // state 2*lane
    const bool val_hi   = (lane <  lb);         // state 2*lane+1
    const bool val_ex   = (lb == Lm);           // state 128 (lane 63)

    float a_lo = (lane == 0) ? 0.f : NEGF;      // virtual alpha_{-1}
    float a_hi = NEGF;
    float a_ex = NEGF;

    if (wave != 0 && Tb > 0) copy_E(0);
    __syncthreads();

    for (int c = 0; c < NCH; ++c) {
        if (wave == 0) {
            const int tbase = c * CH;
            if (tbase < Tb) {
                const int steps = (Tb - tbase) < CH ? (Tb - tbase) : CH;
                const float* eb = Ebuf[c & 1];
                // depth-4 register ring over LDS rows (chunk fully staged,
                // so rows [0,CH) are always valid to prefetch)
                float rc[4], rb[4];
#pragma unroll
                for (int i = 0; i < 4; ++i) {
                    rc[i] = eb[i * ROW + lane];
                    rb[i] = eb[i * ROW + 64];
                }
                for (int i0 = 0; i0 < CH; i0 += 4) {
#pragma unroll
                    for (int j = 0; j < 4; ++j) {
                        const int i = i0 + j;
                        if (i >= steps) break;
                        const float e_c = rc[j];
                        const float e_b = rb[j];
                        const int tn = i + 4;
                        if (tn < CH) {
                            rc[j] = eb[tn * ROW + lane];
                            rb[j] = eb[tn * ROW + 64];
                        }
                        const float p_hi = wave_shr1(a_hi, NEGF); // state 2i-1
                        float n_lo = e_b + lae2(a_lo, p_hi);
                        float n_hi = e_c + lse3_2(a_hi, a_lo, skip ? p_hi : NEGF);
                        float n_ex = e_b + lae2(a_ex, a_hi);
                        a_lo = val_lo ? n_lo : NEGF;
                        a_hi = val_hi ? n_hi : NEGF;
                        a_ex = val_ex ? n_ex : NEGF;
                    }
                    if (i0 + 4 >= steps) break;
                }
            }
        } else {
            // stage chunk c+1 iff the recursion will consume it
            const int n = c + 1;
            if (n < NCH && n * CH < Tb) copy_E(n);
        }
        __syncthreads();   // uniform: all 8 waves, every iteration
    }

    if (wave == 0) {
        const float a_end_blank = (lb == Lm) ? __shfl(a_ex, 63, 64)
                                             : __shfl(a_lo, lb, 64);
        const int   el_lane     = (lb >= 1) ? (lb - 1) : 0;
        const float a_end_label = (lb >= 1) ? __shfl(a_hi, el_lane, 64)
                                            : __shfl(a_lo, 0, 64);
        if (lane == 0) {
            out[b] = -LN2F * lae2(a_end_blank, a_end_label);
        }
    }
}

extern "C" void kernel_launch(void* const* d_in, const int* in_sizes, int n_in,
                              void* d_out, int out_size, void* d_ws, size_t ws_size,
                              hipStream_t stream) {
    const int*   y_true  = (const int*)  d_in[0];
    const float* y_pred  = (const float*)d_in[1];
    const int*   in_len  = (const int*)  d_in[2];
    const int*   lab_len = (const int*)  d_in[3];
    float*       out     = (float*)      d_out;

    ctc_gather<<<dim3(NB * (Tmax / RPB)), dim3(256), 0, stream>>>(
        y_true, y_pred, in_len);
    ctc_rec<<<dim3(NB), dim3(512), 0, stream>>>(
        y_true, in_len, lab_len, out);
}

// Round 8
// 449.038 us; speedup vs baseline: 1.1467x; 1.0761x over previous
//
#include <hip/hip_runtime.h>

// CTC batch cost (keras ctc_batch_cost), forward alpha recursion.
// B=128, T=512, C=1024, L=64, S=2L+1=129, blank = C-1.
//
// R9 (5th resubmit; R3/R4/R6/R7 were GPU-acquisition timeouts, R5 a
// container failure -- kernel never executed): fused single kernel (R6
// structure) + coalesced gather (R8 insight).
// R7 proved the scattered per-lane gather (lane reads row[cls[lane]]) runs
// at 427 GB/s (5% HBM peak, line-serialization bound). R8 proved coalesced
// row reads fix that but the 2-kernel split re-lost the win to a 17 MB
// global round-trip + cold cross-XCD L2 misses + second dispatch.
// R9 fuses both: one kernel, 128 blocks x 512 threads (block = batch b):
//   wave 0:    serial alpha recursion out of LDS (verified exact, absmax=0
//              in R4/R5/R6/R8).
//   waves 1-7: stage whole 4KB y_pred rows COALESCED (4x float4/lane) into
//              a private LDS row buffer, LDS-gather the 64 labels + blank,
//              write log2-domain E row straight into the LDS double buffer.
//              Register double-buffer (va/vb) keeps one row in flight per
//              wave; rows with t >= input_length are skipped.
// LDS: Ebuf 2*64*66*4 = 33.8 KB + rowstage 7*4 KB = 28 KB -> 62.5 KB.
//
// Recursion: lane i owns extended states {2i, 2i+1}; lane 63 also owns
// state 128. Cross-lane dep via DPP wave_shr:1. Log2 domain throughout;
// ln alpha = log2 alpha * ln2 restored at the final loss.
//
// Inputs: d_in[0] y_true i32[B,L]; d_in[1] y_pred f32[B,T,C];
//         d_in[2] input_length i32[B,1]; d_in[3] label_length i32[B,1].
// Output: float [B,1].

constexpr int Tmax   = 512;
constexpr int Cch    = 1024;
constexpr int Lm     = 64;
constexpr int BLANKC = Cch - 1;
constexpr int CH     = 64;            // timesteps per chunk
constexpr int NCH    = Tmax / CH;     // 8
constexpr int ROW    = 66;            // E row stride: 64 labels + blank + pad
constexpr int NB     = 128;           // batch
constexpr int GW     = 7;             // gather waves (waves 1..7)

#define NEGF (-1e9f)
#define EPSF (1e-7f)
#define LN2F (0.69314718055994530942f)

__device__ __forceinline__ float wave_shr1(float src, float fill) {
    int r = __builtin_amdgcn_update_dpp(__float_as_int(fill), __float_as_int(src),
                                        0x138, 0xf, 0xf, false);
    return __int_as_float(r);
}
__device__ __forceinline__ float lae2(float a, float b) {
    float m = fmaxf(a, b);
    return m + __builtin_log2f(__builtin_exp2f(a - m) + __builtin_exp2f(b - m));
}
__device__ __forceinline__ float lse3_2(float a, float b, float c) {
    float m = fmaxf(fmaxf(a, b), c);
    return m + __builtin_log2f(__builtin_exp2f(a - m) +
                               __builtin_exp2f(b - m) +
                               __builtin_exp2f(c - m));
}
__device__ __forceinline__ int clampi(int v, int lo, int hi) {
    return v < lo ? lo : (v > hi ? hi : v);
}

struct R4 { float4 a, b, c, d; };

__global__ __launch_bounds__(512, 1) void ctc_fused(
    const int*   __restrict__ y_true,
    const float* __restrict__ y_pred,
    const int*   __restrict__ in_len,
    const int*   __restrict__ lab_len,
    float*       __restrict__ out)
{
    const int b    = blockIdx.x;
    const int tid  = threadIdx.x;
    const int wave = tid >> 6;
    const int lane = tid & 63;

    __shared__ float Ebuf[2][CH * ROW];     // 33.8 KB double buffer
    __shared__ float rowstage[GW][Cch];     // 28 KB, one 4KB row per gather wave

    const int cls = y_true[b * Lm + lane];  // label of odd state 2*lane+1
    const int Tb  = clampi(in_len[b], 0, Tmax);
    const int lb  = clampi(lab_len[b], 0, Lm);
    const float* __restrict__ base = y_pred + (size_t)b * Tmax * Cch;

    // ---- coalesced gather of chunk c into Ebuf[c&1] (waves 1..7 only) ----
    // wave w handles rows tt = (w-1) + 7k, k = 0..9. Per row: coalesced
    // 4x float4/lane load -> LDS rowstage -> gather cls/blank -> E row.
    // va/vb register double-buffer: row k+1's loads issue between row k's
    // LDS write and its LDS gather (no reg WAR, latency hidden).
    auto gather = [&](int c) {
        const int tbase = c * CH;
        const int tt0   = wave - 1;         // 0..6
        float* lbuf = rowstage[wave - 1];
        R4 va, vb;

        auto ld = [&](R4& v, int k) {
            const int tt = tt0 + GW * k;
            if (tt < CH) {
                const int t = tbase + tt;
                if (t < Tb) {
                    const float4* s = (const float4*)(base + (size_t)t * Cch);
                    v.a = s[lane];
                    v.b = s[64  + lane];
                    v.c = s[128 + lane];
                    v.d = s[192 + lane];
                }
            }
        };
        auto wr = [&](R4& v, int k) -> bool {
            const int tt = tt0 + GW * k;
            if (tt >= CH) return false;
            const int t = tbase + tt;
            if (t >= Tb) return false;
            float4* lb4 = (float4*)lbuf;
            lb4[lane]        = v.a;
            lb4[64  + lane]  = v.b;
            lb4[128 + lane]  = v.c;
            lb4[192 + lane]  = v.d;
            return true;
        };
        auto gr = [&](int k, bool act) {
            if (!act) return;
            const int tt = tt0 + GW * k;
            const float pc = lbuf[cls];
            const float pb = lbuf[BLANKC];  // uniform address -> broadcast
            float* dst = &Ebuf[c & 1][tt * ROW];
            dst[lane] = __builtin_log2f(pc + EPSF);
            if (lane == 0) dst[64] = __builtin_log2f(pb + EPSF);
        };

        ld(va, 0);
        for (int k = 0; k < 10; k += 2) {
            bool a0 = wr(va, k);     ld(vb, k + 1);  gr(k,     a0);
            bool a1 = wr(vb, k + 1); ld(va, k + 2);  gr(k + 1, a1);
        }
    };

    // ---- recursion state (wave 0; harmless elsewhere) ----
    const int  cls_prev = __shfl_up(cls, 1, 64);
    const bool skip     = (lane >= 1) && (cls != cls_prev);
    const bool val_lo   = (lane <= lb);     // state 2*lane
    const bool val_hi   = (lane <  lb);     // state 2*lane+1
    const bool val_ex   = (lb == Lm);       // state 128 (lane 63)

    float a_lo = (lane == 0) ? 0.f : NEGF;  // virtual alpha_{-1}
    float a_hi = NEGF;
    float a_ex = NEGF;

    if (wave != 0) gather(0);
    __syncthreads();

    for (int c = 0; c < NCH; ++c) {
        if (wave == 0) {
            const int tbase = c * CH;
            if (tbase < Tb) {
                const int steps = (Tb - tbase) < CH ? (Tb - tbase) : CH;
                const float* eb = Ebuf[c & 1];
                // depth-4 register ring over LDS rows (chunk fully staged;
                // prefetched rows >= steps are loaded but never consumed)
                float rc[4], rb[4];
#pragma unroll
                for (int i = 0; i < 4; ++i) {
                    rc[i] = eb[i * ROW + lane];
                    rb[i] = eb[i * ROW + 64];
                }
                for (int i0 = 0; i0 < CH; i0 += 4) {
#pragma unroll
                    for (int j = 0; j < 4; ++j) {
                        const int i = i0 + j;
                        if (i >= steps) break;
                        const float e_c = rc[j];
                        const float e_b = rb[j];
                        const int tn = i + 4;
                        if (tn < CH) {
                            rc[j] = eb[tn * ROW + lane];
                            rb[j] = eb[tn * ROW + 64];
                        }
                        const float p_hi = wave_shr1(a_hi, NEGF); // state 2i-1
                        float n_lo = e_b + lae2(a_lo, p_hi);
                        float n_hi = e_c + lse3_2(a_hi, a_lo, skip ? p_hi : NEGF);
                        float n_ex = e_b + lae2(a_ex, a_hi);
                        a_lo = val_lo ? n_lo : NEGF;
                        a_hi = val_hi ? n_hi : NEGF;
                        a_ex = val_ex ? n_ex : NEGF;
                    }
                    if (i0 + 4 >= steps) break;
                }
            }
        } else {
            // stage chunk c+1 iff the recursion will consume it
            const int n = c + 1;
            if (n < NCH && n * CH < Tb) gather(n);
        }
        __syncthreads();   // uniform: all 8 waves, every iteration
    }

    if (wave == 0) {
        const float a_end_blank = (lb == Lm) ? __shfl(a_ex, 63, 64)
                                             : __shfl(a_lo, lb, 64);
        const int   el_lane     = (lb >= 1) ? (lb - 1) : 0;
        const float a_end_label = (lb >= 1) ? __shfl(a_hi, el_lane, 64)
                                            : __shfl(a_lo, 0, 64);
        if (lane == 0) {
            out[b] = -LN2F * lae2(a_end_blank, a_end_label);
        }
    }
}

extern "C" void kernel_launch(void* const* d_in, const int* in_sizes, int n_in,
                              void* d_out, int out_size, void* d_ws, size_t ws_size,
                              hipStream_t stream) {
    const int*   y_true  = (const int*)  d_in[0];
    const float* y_pred  = (const float*)d_in[1];
    const int*   in_len  = (const int*)  d_in[2];
    const int*   lab_len = (const int*)  d_in[3];
    float*       out     = (float*)      d_out;

    ctc_fused<<<dim3(NB), dim3(512), 0, stream>>>(
        y_true, y_pred, in_len, lab_len, out);
}

// Round 10
// 415.556 us; speedup vs baseline: 1.2391x; 1.0806x over previous
//
#include <hip/hip_runtime.h>

// CTC batch cost (keras ctc_batch_cost), forward alpha recursion.
// B=128, T=512, C=1024, L=64, S=2L+1=129, blank = C-1.
//
// R10 (resubmit; prior round was a GPU-acquisition timeout, never ran):
// global_load_lds gather. R9's rocprof showed 48 MB of HBM WRITES on
// a kernel that stores 512 bytes -> the R4 va/vb register double-buffer
// was demoted to scratch (by-ref lambda params under divergent guards;
// VGPR_Count=52 too small to hold 2x16-VGPR structs). Every staged row
// paid a scratch round-trip -> latency-bound 825 GB/s, 186 us.
// Fix: stage rows with __builtin_amdgcn_global_load_lds width=16 (direct
// HBM->LDS, no VGPR/scratch round-trip; compiler never auto-emits it).
// Structure otherwise identical to the verified R6/R9 skeleton:
//   one kernel, 128 blocks x 512 threads (block = batch b):
//   wave 0:    serial alpha recursion out of LDS (verified exact,
//              absmax=0 in R4/R5/R6/R8/R9).
//   waves 1-7: per chunk, wave w stages rows tt=(w-1)+7k (k=0..9) of
//              y_pred COALESCED into a private 4KB LDS row buffer via
//              4x global_load_lds dwordx4 (LDS dest = uniform base +
//              lane*16, linear -> matches contiguous row exactly),
//              s_waitcnt vmcnt(0), LDS-gather the 64 labels + blank,
//              write log2-domain E row into the LDS double buffer.
//              7 waves x 4KB = 28KB in flight/CU >= Little's-law ~19KB.
// LDS: Ebuf 2*64*66*4 = 33.8 KB + rowstage 7*4 KB = 28 KB -> 62.5 KB.
//
// Recursion: lane i owns extended states {2i, 2i+1}; lane 63 also owns
// state 128. Cross-lane dep via DPP wave_shr:1. Log2 domain throughout;
// ln alpha = log2 alpha * ln2 restored at the final loss.
//
// Inputs: d_in[0] y_true i32[B,L]; d_in[1] y_pred f32[B,T,C];
//         d_in[2] input_length i32[B,1]; d_in[3] label_length i32[B,1].
// Output: float [B,1].

constexpr int Tmax   = 512;
constexpr int Cch    = 1024;
constexpr int Lm     = 64;
constexpr int BLANKC = Cch - 1;
constexpr int CH     = 64;            // timesteps per chunk
constexpr int NCH    = Tmax / CH;     // 8
constexpr int ROW    = 66;            // E row stride: 64 labels + blank + pad
constexpr int NB     = 128;           // batch
constexpr int GW     = 7;             // gather waves (waves 1..7)

#define NEGF (-1e9f)
#define EPSF (1e-7f)
#define LN2F (0.69314718055994530942f)

__device__ __forceinline__ float wave_shr1(float src, float fill) {
    int r = __builtin_amdgcn_update_dpp(__float_as_int(fill), __float_as_int(src),
                                        0x138, 0xf, 0xf, false);
    return __int_as_float(r);
}
__device__ __forceinline__ float lae2(float a, float b) {
    float m = fmaxf(a, b);
    return m + __builtin_log2f(__builtin_exp2f(a - m) + __builtin_exp2f(b - m));
}
__device__ __forceinline__ float lse3_2(float a, float b, float c) {
    float m = fmaxf(fmaxf(a, b), c);
    return m + __builtin_log2f(__builtin_exp2f(a - m) +
                               __builtin_exp2f(b - m) +
                               __builtin_exp2f(c - m));
}
__device__ __forceinline__ int clampi(int v, int lo, int hi) {
    return v < lo ? lo : (v > hi ? hi : v);
}

__global__ __launch_bounds__(512, 1) void ctc_fused(
    const int*   __restrict__ y_true,
    const float* __restrict__ y_pred,
    const int*   __restrict__ in_len,
    const int*   __restrict__ lab_len,
    float*       __restrict__ out)
{
    const int b    = blockIdx.x;
    const int tid  = threadIdx.x;
    const int wave = tid >> 6;
    const int lane = tid & 63;

    __shared__ float Ebuf[2][CH * ROW];     // 33.8 KB double buffer
    __shared__ float rowstage[GW][Cch];     // 28 KB, one 4KB row per gather wave

    const int cls = y_true[b * Lm + lane];  // label of odd state 2*lane+1
    const int Tb  = clampi(in_len[b], 0, Tmax);
    const int lb  = clampi(lab_len[b], 0, Lm);
    const float* __restrict__ base = y_pred + (size_t)b * Tmax * Cch;

    // ---- coalesced gather of chunk c into Ebuf[c&1] (waves 1..7 only) ----
    // wave w handles rows tt = (w-1) + 7k, k = 0..9. Per row:
    //   4x global_load_lds dwordx4 (HBM -> LDS direct, 1KB each; LDS dest
    //   uniform base + lane*16 == linear row layout), vmcnt(0), LDS-gather
    //   cls/blank, log2, write E row. All guards are wave-uniform
    //   (tt, t, Tb lane-invariant) -> full exec mask at each gload_lds.
    auto gather = [&](int c) {
        const int tbase = c * CH;
        const int tt0   = wave - 1;         // 0..6
        float* lbuf = rowstage[wave - 1];
        for (int k = 0; k < 10; ++k) {
            const int tt = tt0 + GW * k;
            if (tt >= CH) break;
            const int t = tbase + tt;
            if (t >= Tb) continue;          // wave-uniform (t monotone in k)
            const float* src = base + (size_t)t * Cch;
#pragma unroll
            for (int j = 0; j < 4; ++j) {
                __builtin_amdgcn_global_load_lds(
                    (const __attribute__((address_space(1))) void*)
                        (src + j * 256 + lane * 4),
                    (__attribute__((address_space(3))) void*)(lbuf + j * 256),
                    16, 0, 0);
            }
            asm volatile("s_waitcnt vmcnt(0)" ::: "memory");
            const float pc = lbuf[cls];
            const float pb = lbuf[BLANKC];  // uniform address -> broadcast
            float* dst = &Ebuf[c & 1][tt * ROW];
            dst[lane] = __builtin_log2f(pc + EPSF);
            if (lane == 0) dst[64] = __builtin_log2f(pb + EPSF);
            // drain the lbuf ds_reads before next row's gload_lds overwrites
            asm volatile("s_waitcnt lgkmcnt(0)" ::: "memory");
        }
    };

    // ---- recursion state (wave 0; harmless elsewhere) ----
    const int  cls_prev = __shfl_up(cls, 1, 64);
    const bool skip     = (lane >= 1) && (cls != cls_prev);
    const bool val_lo   = (lane <= lb);     // state 2*lane
    const bool val_hi   = (lane <  lb);     // state 2*lane+1
    const bool val_ex   = (lb == Lm);       // state 128 (lane 63)

    float a_lo = (lane == 0) ? 0.f : NEGF;  // virtual alpha_{-1}
    float a_hi = NEGF;
    float a_ex = NEGF;

    if (wave != 0) gather(0);
    __syncthreads();

    for (int c = 0; c < NCH; ++c) {
        if (wave == 0) {
            const int tbase = c * CH;
            if (tbase < Tb) {
                const int steps = (Tb - tbase) < CH ? (Tb - tbase) : CH;
                const float* eb = Ebuf[c & 1];
                // depth-4 register ring over LDS rows (chunk fully staged;
                // prefetched rows >= steps are loaded but never consumed)
                float rc[4], rb[4];
#pragma unroll
                for (int i = 0; i < 4; ++i) {
                    rc[i] = eb[i * ROW + lane];
                    rb[i] = eb[i * ROW + 64];
                }
                for (int i0 = 0; i0 < CH; i0 += 4) {
#pragma unroll
                    for (int j = 0; j < 4; ++j) {
                        const int i = i0 + j;
                        if (i >= steps) break;
                        const float e_c = rc[j];
                        const float e_b = rb[j];
                        const int tn = i + 4;
                        if (tn < CH) {
                            rc[j] = eb[tn * ROW + lane];
                            rb[j] = eb[tn * ROW + 64];
                        }
                        const float p_hi = wave_shr1(a_hi, NEGF); // state 2i-1
                        float n_lo = e_b + lae2(a_lo, p_hi);
                        float n_hi = e_c + lse3_2(a_hi, a_lo, skip ? p_hi : NEGF);
                        float n_ex = e_b + lae2(a_ex, a_hi);
                        a_lo = val_lo ? n_lo : NEGF;
                        a_hi = val_hi ? n_hi : NEGF;
                        a_ex = val_ex ? n_ex : NEGF;
                    }
                    if (i0 + 4 >= steps) break;
                }
            }
        } else {
            // stage chunk c+1 iff the recursion will consume it
            const int n = c + 1;
            if (n < NCH && n * CH < Tb) gather(n);
        }
        __syncthreads();   // uniform: all 8 waves, every iteration
    }

    if (wave == 0) {
        const float a_end_blank = (lb == Lm) ? __shfl(a_ex, 63, 64)
                                             : __shfl(a_lo, lb, 64);
        const int   el_lane     = (lb >= 1) ? (lb - 1) : 0;
        const float a_end_label = (lb >= 1) ? __shfl(a_hi, el_lane, 64)
                                            : __shfl(a_lo, 0, 64);
        if (lane == 0) {
            out[b] = -LN2F * lae2(a_end_blank, a_end_label);
        }
    }
}

extern "C" void kernel_launch(void* const* d_in, const int* in_sizes, int n_in,
                              void* d_out, int out_size, void* d_ws, size_t ws_size,
                              hipStream_t stream) {
    const int*   y_true  = (const int*)  d_in[0];
    const float* y_pred  = (const float*)d_in[1];
    const int*   in_len  = (const int*)  d_in[2];
    const int*   lab_len = (const int*)  d_in[3];
    float*       out     = (float*)      d_out;

    ctc_fused<<<dim3(NB), dim3(512), 0, stream>>>(
        y_true, y_pred, in_len, lab_len, out);
}